// Round 2
// baseline (1076.637 us; speedup 1.0000x reference)
//
#include <hip/hip_runtime.h>
#include <stdint.h>

// BaseOpenSetClassifier: per-pixel sq-euclid distances to K templates + min/argmin.
// B=16, N=16384, D=64, K=64, thresholds {0.5, 1.0}.
//
// R2 design (fixing R1's VMEM-issue bottleneck):
//  - Templates staged global->LDS with __builtin_amdgcn_global_load_lds (16B/lane,
//    fully coalesced: 256 threads cover one k's 16n x 256B = 4KB tile contiguously).
//  - lane=(b=t&15, nl=t>>4): wave w computes rows nl=4w..4w+3 AND stages exactly
//    those rows (i>>4 = 4w..4w+3 for its lanes) -> waves fully independent:
//    NO __syncthreads anywhere; per-wave depth-4 LDS ring + s_waitcnt vmcnt(3).
//  - b-reuse (16 lanes same t-row) served by LDS broadcast ds_read_b128
//    (4 distinct addrs/wave, conflict-free).
//  - x[b][n][:] = 16 float4 in registers, loaded once.

#define BB 16
#define NN 16384
#define DD 64
#define KK 64
#define NT 16      // pixels per block -> 256 threads, 1024 blocks = 4 blocks/CU
#define DEPTH 4    // LDS ring slots (16 KB)

// s_waitcnt with only vmcnt constrained (expcnt=7, lgkmcnt=15 -> no wait)
#define WAITCNT_VM(n) __builtin_amdgcn_s_waitcnt(((n)&0xF) | (0x7<<4) | (0xF<<8) | ((((n)>>4)&0x3)<<14))

__device__ __forceinline__ void load16_to_lds(const float* src, float* ldsDst) {
    auto* g = reinterpret_cast<const uint32_t __attribute__((address_space(1)))*>(
        reinterpret_cast<uintptr_t>(src));
    auto* l = reinterpret_cast<uint32_t __attribute__((address_space(3)))*>(
        reinterpret_cast<uintptr_t>(ldsDst));
    __builtin_amdgcn_global_load_lds(g, l, 16, 0, 0);
}

__global__ __launch_bounds__(256, 4)
void openset_kernel(const float* __restrict__ x,     // [B,N,D]
                    const float* __restrict__ tmpl,  // [K,N,D]
                    const int*   __restrict__ tcls,  // [K]
                    float*       __restrict__ out) { // [2*B*N | B*N | B*N]
    __shared__ float lds[DEPTH * NT * DD];           // 4 slots x 4 KB

    const int t    = threadIdx.x;
    const int b    = t & 15;
    const int nl   = t >> 4;          // 0..15 (also the staging row for thread t)
    const int wave = t >> 6;          // 0..3
    const int n0   = blockIdx.x * NT;
    const int n    = n0 + nl;

    // Staging source for this thread: row (n0 + t>>4), 16B chunk (t&15).
    // Per k, add k*NN*DD. Destination: wave-uniform base; HW adds lane*16B.
    const float* tsrc  = tmpl + (size_t)(n0 + (t >> 4)) * DD + (t & 15) * 4;
    float* const ldswb = lds + wave * 256;           // + slot*1024 floats

    // x vector for (b, n): 64 floats = 16 float4 in registers (issued first,
    // overlaps with the prologue template loads).
    const float4* xp = (const float4*)(x + ((size_t)b * NN + n) * DD);
    float4 xv[16];
#pragma unroll
    for (int j = 0; j < 16; ++j) xv[j] = xp[j];

    // Prologue: prefetch k = 0,1,2 into ring slots 0,1,2.
#pragma unroll
    for (int k = 0; k < DEPTH - 1; ++k)
        load16_to_lds(tsrc + (size_t)k * NN * DD, ldswb + k * (NT * DD));

    float best  = 3.4e38f;
    int   bestk = 0;

    const float4* ldsr = (const float4*)lds + nl * 16;   // + slot*256 f4

#pragma unroll 4
    for (int k = 0; k < KK; ++k) {
        const int kp = k + (DEPTH - 1);
        if (kp < KK)
            load16_to_lds(tsrc + (size_t)kp * NN * DD,
                          ldswb + (kp & (DEPTH - 1)) * (NT * DD));

        // Wait until tile k has landed (keep up to 3 newer tiles in flight).
        if (k < KK - (DEPTH - 1)) { WAITCNT_VM(DEPTH - 1); } else { WAITCNT_VM(0); }

        const float4* tk = ldsr + (k & (DEPTH - 1)) * (NT * DD / 4);
        float s0 = 0.f, s1 = 0.f, s2 = 0.f, s3 = 0.f;
#pragma unroll
        for (int j = 0; j < 16; ++j) {
            float4 tv = tk[j];
            float d0 = xv[j].x - tv.x;
            float d1 = xv[j].y - tv.y;
            float d2 = xv[j].z - tv.z;
            float d3 = xv[j].w - tv.w;
            s0 = fmaf(d0, d0, s0);
            s1 = fmaf(d1, d1, s1);
            s2 = fmaf(d2, d2, s2);
            s3 = fmaf(d3, d3, s3);
        }
        float dist = (s0 + s1) + (s2 + s3);
        if (dist < best) { best = dist; bestk = k; }
    }

    const size_t BN = (size_t)BB * NN;
    const size_t o  = (size_t)b * NN + n;
    out[o]          = (best <= 0.5f) ? 1.0f : 0.0f;  // masks[0]
    out[BN + o]     = (best <= 1.0f) ? 1.0f : 0.0f;  // masks[1]
    out[2 * BN + o] = best;                          // min_dists
    out[3 * BN + o] = (float)tcls[bestk];            // pred_classes
}

extern "C" void kernel_launch(void* const* d_in, const int* in_sizes, int n_in,
                              void* d_out, int out_size, void* d_ws, size_t ws_size,
                              hipStream_t stream) {
    const float* x    = (const float*)d_in[0];   // frame_embeddings [16,16384,64]
    const float* tmpl = (const float*)d_in[1];   // templates       [64,16384,64]
    const int*   tcls = (const int*)d_in[2];     // template_classes [64]
    float* out = (float*)d_out;

    dim3 grid(NN / NT);   // 1024
    dim3 block(256);
    openset_kernel<<<grid, block, 0, stream>>>(x, tmpl, tcls, out);
}

// Round 3
// 1008.084 us; speedup vs baseline: 1.0680x; 1.0680x over previous
//
#include <hip/hip_runtime.h>
#include <stdint.h>

// BaseOpenSetClassifier: per-pixel sq-euclid distance to K templates + min/argmin.
// B=16, N=16384, D=64, K=64, thresholds {0.5, 1.0}.
//
// R3 design: 4b x 4k register-tiled, NO LDS, no barriers.
//  - wave per pixel n; lane = kq*4+bq (kq in [0,16), bq in [0,4)).
//  - thread owns acc[4][4] for b = bq*4+i, k = kq*4+j; d-loop in 16 float4 steps
//    with ping-pong fragment buffers (max ~64 live operand VGPRs -- no big
//    per-thread arrays, avoiding R1/R2's spill catastrophe at VGPR<=64).
//  - per pixel per wave: 128 VMEM instrs (vs R1's 2048) -- t reads deliver
//    16 distinct 16B chunks/instr; 64B-sector remainder reused by the next 3
//    d-steps (L1/L2 absorbs), so HBM traffic stays ~once per byte.
//  - min/argmin: thread-local over j (strict <, ascending k => first-index
//    tie rule matches jnp.argmin), then 4-level __shfl_xor reduce over kq
//    with (val, idx) lexicographic compare.
//  - stores: lanes kq<4 each own one output type (mask0, mask1, dist, cls).

#define BB 16
#define NN 16384
#define DD 64
#define KK 64

__global__ __launch_bounds__(256, 4)
void openset_kernel(const float* __restrict__ x,     // [B,N,D]
                    const float* __restrict__ tmpl,  // [K,N,D]
                    const int*   __restrict__ tcls,  // [K]
                    float*       __restrict__ out) { // [2*B*N | B*N | B*N]
    const int lane = threadIdx.x & 63;
    const int wave = threadIdx.x >> 6;
    const int n    = blockIdx.x * 4 + wave;   // wave per pixel
    const int bq   = lane & 3;                // b-tile: b = bq*4 + i
    const int kq   = lane >> 2;               // k-tile: k = kq*4 + j

    // Row base pointers (float4 granularity). b-rows stride NN*DD floats.
    const float4* xP[4];
    const float4* tP[4];
#pragma unroll
    for (int i = 0; i < 4; ++i)
        xP[i] = (const float4*)(x + ((size_t)(bq * 4 + i) * NN + n) * DD);
#pragma unroll
    for (int j = 0; j < 4; ++j)
        tP[j] = (const float4*)(tmpl + ((size_t)(kq * 4 + j) * NN + n) * DD);

    float acc[4][4] = {};

    // Ping-pong fragments: current (cx/ct), next (nx/nt).
    float4 cx[4], ct[4], nx[4], nt[4];
#pragma unroll
    for (int i = 0; i < 4; ++i) { cx[i] = xP[i][0]; ct[i] = tP[i][0]; }

#pragma unroll
    for (int s = 0; s < 16; ++s) {
        if (s < 15) {
#pragma unroll
            for (int i = 0; i < 4; ++i) { nx[i] = xP[i][s + 1]; nt[i] = tP[i][s + 1]; }
        }
#pragma unroll
        for (int i = 0; i < 4; ++i) {
#pragma unroll
            for (int j = 0; j < 4; ++j) {
                float d0 = cx[i].x - ct[j].x;
                float d1 = cx[i].y - ct[j].y;
                float d2 = cx[i].z - ct[j].z;
                float d3 = cx[i].w - ct[j].w;
                float a = acc[i][j];
                a = fmaf(d0, d0, a);
                a = fmaf(d1, d1, a);
                a = fmaf(d2, d2, a);
                a = fmaf(d3, d3, a);
                acc[i][j] = a;
            }
        }
        if (s < 15) {
#pragma unroll
            for (int i = 0; i < 4; ++i) { cx[i] = nx[i]; ct[i] = nt[i]; }
        }
    }

    // Thread-local min over this thread's 4 k's (ascending j => first-index ties).
    float md[4];
    int   mi[4];
#pragma unroll
    for (int i = 0; i < 4; ++i) {
        md[i] = acc[i][0]; mi[i] = kq * 4;
#pragma unroll
        for (int j = 1; j < 4; ++j) {
            if (acc[i][j] < md[i]) { md[i] = acc[i][j]; mi[i] = kq * 4 + j; }
        }
    }

    // Cross-lane reduce over kq (lane xor 4,8,16,32), (val,idx) lexicographic.
#pragma unroll
    for (int m = 4; m < 64; m <<= 1) {
#pragma unroll
        for (int i = 0; i < 4; ++i) {
            float od = __shfl_xor(md[i], m);
            int   oi = __shfl_xor(mi[i], m);
            if (od < md[i] || (od == md[i] && oi < mi[i])) { md[i] = od; mi[i] = oi; }
        }
    }

    // Stores: lane's kq (<4) selects output type tau: 0=mask@0.5, 1=mask@1.0,
    // 2=min_dist, 3=pred_class. 16 active lanes x 4 b-rows each.
    if (kq < 4) {
        const size_t BN = (size_t)BB * NN;
#pragma unroll
        for (int i = 0; i < 4; ++i) {
            const int b = bq * 4 + i;
            const size_t o = (size_t)b * NN + n;
            float v;
            if (kq == 0)      v = (md[i] <= 0.5f) ? 1.0f : 0.0f;
            else if (kq == 1) v = (md[i] <= 1.0f) ? 1.0f : 0.0f;
            else if (kq == 2) v = md[i];
            else              v = (float)tcls[mi[i]];
            out[(size_t)kq * BN + o] = v;
        }
    }
}

extern "C" void kernel_launch(void* const* d_in, const int* in_sizes, int n_in,
                              void* d_out, int out_size, void* d_ws, size_t ws_size,
                              hipStream_t stream) {
    const float* x    = (const float*)d_in[0];   // frame_embeddings [16,16384,64]
    const float* tmpl = (const float*)d_in[1];   // templates       [64,16384,64]
    const int*   tcls = (const int*)d_in[2];     // template_classes [64]
    float* out = (float*)d_out;

    dim3 grid(NN / 4);    // 4096 blocks, 1 wave per pixel
    dim3 block(256);
    openset_kernel<<<grid, block, 0, stream>>>(x, tmpl, tcls, out);
}

// Round 4
// 531.516 us; speedup vs baseline: 2.0256x; 1.8966x over previous
//
#include <hip/hip_runtime.h>
#include <stdint.h>

// BaseOpenSetClassifier: per-pixel sq-euclid distance to K templates + min/argmin.
// B=16, N=16384, D=64, K=64, thresholds {0.5, 1.0}.
//
// R4 = R3's 4b x 4k register tiling with the spill cause removed.
// EVIDENCE (R2/R3): __launch_bounds__(256,4) => VGPR_Count 64 + ~1.2 GB scratch
// WRITE_SIZE (logical writes are 4 MB) -> allocator was budgeting for 8 waves/EU
// and spilling ~50 regs/thread. Fix: __launch_bounds__(256,1) (budget 512,
// pressure-driven ~120) and no manual ping-pong buffers.
//
//  - wave per pixel n; lane = kq*4+bq (kq in [0,16), bq in [0,4)).
//  - thread owns acc[4][4] for b = bq*4+i, k = kq*4+j; 16 d-steps of float4.
//  - numerics: per-step partial p (depth-4 fmaf chain) then acc += p ->
//    acc chain length 16 (R1-grade, absmax 0.5) vs R3's 64-chain (absmax 3.0).
//  - min/argmin: thread-local over j (strict <, ascending k), then 4-level
//    __shfl_xor reduce over kq with (val, idx) lexicographic compare ->
//    first-index tie rule matches jnp.argmin.
//  - stores: lanes kq<4 each own one output section (mask0, mask1, dist, cls).

#define BB 16
#define NN 16384
#define DD 64
#define KK 64

__global__ __launch_bounds__(256, 1)
void openset_kernel(const float* __restrict__ x,     // [B,N,D]
                    const float* __restrict__ tmpl,  // [K,N,D]
                    const int*   __restrict__ tcls,  // [K]
                    float*       __restrict__ out) { // [2*B*N | B*N | B*N]
    const int lane = threadIdx.x & 63;
    const int wave = threadIdx.x >> 6;
    const int n    = blockIdx.x * 4 + wave;   // wave per pixel
    const int bq   = lane & 3;                // b = bq*4 + i
    const int kq   = lane >> 2;               // k = kq*4 + j

    // Runtime bases; per-row offsets i*NN*DD / j*NN*DD are compile-time consts.
    const float* xb = x    + ((size_t)(bq * 4) * NN + n) * DD;
    const float* tb = tmpl + ((size_t)(kq * 4) * NN + n) * DD;

    float acc[4][4] = {};

#pragma unroll 2
    for (int s = 0; s < 16; ++s) {
        float4 xs[4], ts[4];
#pragma unroll
        for (int i = 0; i < 4; ++i)
            xs[i] = *(const float4*)(xb + (size_t)i * NN * DD + s * 4);
#pragma unroll
        for (int j = 0; j < 4; ++j)
            ts[j] = *(const float4*)(tb + (size_t)j * NN * DD + s * 4);

#pragma unroll
        for (int i = 0; i < 4; ++i) {
#pragma unroll
            for (int j = 0; j < 4; ++j) {
                float d0 = xs[i].x - ts[j].x;
                float d1 = xs[i].y - ts[j].y;
                float d2 = xs[i].z - ts[j].z;
                float d3 = xs[i].w - ts[j].w;
                float p = d0 * d0;
                p = fmaf(d1, d1, p);
                p = fmaf(d2, d2, p);
                p = fmaf(d3, d3, p);
                acc[i][j] += p;          // acc chain length 16, not 64
            }
        }
    }

    // Thread-local min over this thread's 4 k's (ascending j => first-index ties).
    float md[4];
    int   mi[4];
#pragma unroll
    for (int i = 0; i < 4; ++i) {
        md[i] = acc[i][0]; mi[i] = kq * 4;
#pragma unroll
        for (int j = 1; j < 4; ++j) {
            if (acc[i][j] < md[i]) { md[i] = acc[i][j]; mi[i] = kq * 4 + j; }
        }
    }

    // Cross-lane reduce over kq (lane xor 4,8,16,32), (val,idx) lexicographic.
#pragma unroll
    for (int m = 4; m < 64; m <<= 1) {
#pragma unroll
        for (int i = 0; i < 4; ++i) {
            float od = __shfl_xor(md[i], m);
            int   oi = __shfl_xor(mi[i], m);
            if (od < md[i] || (od == md[i] && oi < mi[i])) { md[i] = od; mi[i] = oi; }
        }
    }

    // Stores: lane's kq (<4) selects output section: 0=mask@0.5, 1=mask@1.0,
    // 2=min_dist, 3=pred_class. 16 active lanes x 4 b-rows each.
    if (kq < 4) {
        const size_t BN = (size_t)BB * NN;
#pragma unroll
        for (int i = 0; i < 4; ++i) {
            const int b = bq * 4 + i;
            const size_t o = (size_t)b * NN + n;
            float v;
            if (kq == 0)      v = (md[i] <= 0.5f) ? 1.0f : 0.0f;
            else if (kq == 1) v = (md[i] <= 1.0f) ? 1.0f : 0.0f;
            else if (kq == 2) v = md[i];
            else              v = (float)tcls[mi[i]];
            out[(size_t)kq * BN + o] = v;
        }
    }
}

extern "C" void kernel_launch(void* const* d_in, const int* in_sizes, int n_in,
                              void* d_out, int out_size, void* d_ws, size_t ws_size,
                              hipStream_t stream) {
    const float* x    = (const float*)d_in[0];   // frame_embeddings [16,16384,64]
    const float* tmpl = (const float*)d_in[1];   // templates       [64,16384,64]
    const int*   tcls = (const int*)d_in[2];     // template_classes [64]
    float* out = (float*)d_out;

    dim3 grid(NN / 4);    // 4096 blocks, 1 wave per pixel
    dim3 block(256);
    openset_kernel<<<grid, block, 0, stream>>>(x, tmpl, tcls, out);
}

// Round 6
// 441.598 us; speedup vs baseline: 2.4380x; 1.2036x over previous
//
#include <hip/hip_runtime.h>
#include <stdint.h>

// BaseOpenSetClassifier: per-pixel sq-euclid distance to K templates + min/argmin.
// B=16, N=16384, D=64, K=64, thresholds {0.5, 1.0}.
//
// R6 = R5's coalesced-load + cross-lane-reduce design with the coverage bug
// fixed. R5 FAILED because n AND wb were both derived from the wave index ->
// only the diagonal 1/4 of (b-quad, pixel) pairs were computed (output matched
// the all-zero stub's absmax exactly). Now: block = ONE pixel (grid = NN),
// wave wv covers b = 4*wv..4*wv+3 -> full coverage, and all 4 waves read the
// SAME template rows -> 4x reuse via same-CU L1/MSHR merge, HBM stays
// compulsory (~324 MB).
//
//  - lane = (k4 = lane>>4, d16 = lane&15); t-load per 4-k chunk: 4 rows x 256B
//    = 1024B unique per instruction (dense; d is in the lane index).
//  - per chunk: lane computes 4 partials (its 4 b x its 16B d-slice vs
//    t[cb+k4]); halving butterfly over lane bits 0,1 redistributes b while
//    reducing d (each lane keeps b = wb + 2*bit0 + bit1), then xor-4/xor-8
//    adds complete the 64-d tree sum (accurate: absmax ~0.5 expected).
//  - running (val,idx)-lex min per lane over its k's; final argmin across k4
//    groups via xor-16/32; first-index tie rule matches jnp.argmin.
//  - no LDS arrays, no barriers; __launch_bounds__(256,1) -- NEVER (256,4):
//    R2/R3 showed it caps VGPR at 64 and generates ~1 GB scratch traffic.

#define BB 16
#define NN 16384
#define DD 64
#define KK 64

__global__ __launch_bounds__(256, 1)
void openset_kernel(const float* __restrict__ x,     // [B,N,D]
                    const float* __restrict__ tmpl,  // [K,N,D]
                    const int*   __restrict__ tcls,  // [K]
                    float*       __restrict__ out) { // [2*B*N | B*N | B*N]
    const int lane = threadIdx.x & 63;
    const int wv   = threadIdx.x >> 6;
    const int n    = blockIdx.x;            // block = one pixel
    const int d16  = lane & 15;             // d-slice: floats d16*4 .. d16*4+3
    const int k4   = lane >> 4;             // k-sub within each 4-k chunk
    const int wb   = wv * 4;                // wave's b-base (4 waves cover 16 b)

    // x fragments: wave's 4 b-rows, this lane's 16B d-slice.
    float4 xv[4];
#pragma unroll
    for (int i = 0; i < 4; ++i)
        xv[i] = *(const float4*)(x + ((size_t)(wb + i) * NN + n) * DD + d16 * 4);

    const float* tb = tmpl + ((size_t)k4 * NN + n) * DD + d16 * 4;

    float bestd = 3.4e38f;
    int   bestk = 0;

    const bool u0 = (lane & 1) != 0;
    const bool u1 = (lane & 2) != 0;

#pragma unroll 8
    for (int cb = 0; cb < KK; cb += 4) {
        // One dense load: 4 k-rows (k4) x 256B (d16) = 1024B unique.
        float4 tv = *(const float4*)(tb + (size_t)cb * NN * DD);

        float p[4];
#pragma unroll
        for (int i = 0; i < 4; ++i) {
            float d0 = xv[i].x - tv.x;
            float d1 = xv[i].y - tv.y;
            float d2 = xv[i].z - tv.z;
            float d3 = xv[i].w - tv.w;
            p[i] = fmaf(d3, d3, fmaf(d2, d2, fmaf(d1, d1, d0 * d0)));
        }

        // Halving butterfly over lane bits 0,1: 4 partials -> 1 full-b partial.
        // After xor-1: lane bit0=B holds {q0: i=2B, q1: i=2B+1}, d-pair summed.
        float a0 = u0 ? p[2] : p[0];
        float s0 = u0 ? p[0] : p[2];
        float a1 = u0 ? p[3] : p[1];
        float s1 = u0 ? p[1] : p[3];
        float q0 = a0 + __shfl_xor(s0, 1);
        float q1 = a1 + __shfl_xor(s1, 1);
        // xor-2: keep i = 2*bit0 + bit1; d-quad summed.
        float a  = u1 ? q1 : q0;
        float s  = u1 ? q0 : q1;
        float r  = a + __shfl_xor(s, 2);
        // Plain adds over lane bits 2,3 complete the 64-d tree sum.
        r += __shfl_xor(r, 4);
        r += __shfl_xor(r, 8);

        // r = dist(b = wb + 2*bit0 + bit1, k = cb + k4).
        const int k = cb + k4;
        if (r < bestd || (r == bestd && k < bestk)) { bestd = r; bestk = k; }
    }

    // Argmin across the 4 k4 groups (lane bits 4,5), (val,idx) lexicographic.
#pragma unroll
    for (int m = 16; m < 64; m <<= 1) {
        float od = __shfl_xor(bestd, m);
        int   ok = __shfl_xor(bestk, m);
        if (od < bestd || (od == bestd && ok < bestk)) { bestd = od; bestk = ok; }
    }

    // Lanes 0..3 hold final (bestd,bestk) for b = wb + 2*bit0 + bit1.
    if (lane < 4) {
        const int b = wb + 2 * (lane & 1) + ((lane >> 1) & 1);
        const size_t BN = (size_t)BB * NN;
        const size_t o  = (size_t)b * NN + n;
        out[o]          = (bestd <= 0.5f) ? 1.0f : 0.0f;  // masks[0] @0.5
        out[BN + o]     = (bestd <= 1.0f) ? 1.0f : 0.0f;  // masks[1] @1.0
        out[2 * BN + o] = bestd;                          // min_dists
        out[3 * BN + o] = (float)tcls[bestk];             // pred_classes
    }
}

extern "C" void kernel_launch(void* const* d_in, const int* in_sizes, int n_in,
                              void* d_out, int out_size, void* d_ws, size_t ws_size,
                              hipStream_t stream) {
    const float* x    = (const float*)d_in[0];   // frame_embeddings [16,16384,64]
    const float* tmpl = (const float*)d_in[1];   // templates       [64,16384,64]
    const int*   tcls = (const int*)d_in[2];     // template_classes [64]
    float* out = (float*)d_out;

    dim3 grid(NN);        // 16384 blocks: block = pixel, 4 waves = 16 b
    dim3 block(256);
    openset_kernel<<<grid, block, 0, stream>>>(x, tmpl, tcls, out);
}

// Round 7
// 421.400 us; speedup vs baseline: 2.5549x; 1.0479x over previous
//
#include <hip/hip_runtime.h>
#include <stdint.h>

// BaseOpenSetClassifier: per-pixel sq-euclid distance to K templates + min/argmin.
// B=16, N=16384, D=64, K=64, thresholds {0.5, 1.0}.
//
// R7 = R6's verified reduce skeleton, VALU-diet edition.
// EVIDENCE (R6): VALUBusy 59% (~100 us busy) at 168 us, hbm 1.2 TB/s, DS pipe
// ~5 shuffles/16 dists -> issue-bound on reduction overhead. Changes:
//  - lane = (k8 = lane>>3, d8 = lane&7): 8-k chunks, 2 dense loads/chunk;
//    butterfly = SAME R6 logic over lane bits 0,1 + single xor-4 add ->
//    2 shuffles + ~11 overhead instrs per 16 dists (was 5 + ~20).
//  - float2 ext-vector math -> v_pk_fma_f32/v_pk_mul_f32 (packed fp32).
//  - __builtin_amdgcn_ds_swizzle for in-loop shuffles; dead lex tie-clause
//    dropped (later k always larger); bestcb via inline-const cndmask.
//  - XCD swizzle n = (blk&7)<<11 | blk>>3: consecutive n (same 64B out line)
//    stays on one XCD -> fixes R6's 8x write amplification (33 MB vs 4 MB).
//  - __launch_bounds__(256,1) -- NEVER (256,4): forces VGPR<=64 + ~1GB spills.

#define BB 16
#define NN 16384
#define DD 64
#define KK 64

typedef float v2f __attribute__((ext_vector_type(2)));

template <int PAT>
__device__ __forceinline__ float swz(float v) {
    return __int_as_float(__builtin_amdgcn_ds_swizzle(__float_as_int(v), PAT));
}

__global__ __launch_bounds__(256, 1)
void openset_kernel(const float* __restrict__ x,     // [B,N,D]
                    const float* __restrict__ tmpl,  // [K,N,D]
                    const int*   __restrict__ tcls,  // [K]
                    float*       __restrict__ out) { // [2*B*N | B*N | B*N]
    const int lane = threadIdx.x & 63;
    const int wv   = threadIdx.x >> 6;
    // XCD-aware pixel swizzle: blocks on XCD i (= blk%8) own n in [i*2048, ...).
    const int n    = ((blockIdx.x & 7) << 11) | (blockIdx.x >> 3);
    const int d8   = lane & 7;              // d-slice: floats 4*d8 (+32*half)
    const int k8   = lane >> 3;             // k-sub within each 8-k chunk
    const int wb   = wv * 4;                // wave's b-base (4 waves cover 16 b)

    // x fragments: 4 b-rows x 2 halves, as packed float2 pairs.
    v2f xlo[4][2], xhi[4][2];
#pragma unroll
    for (int i = 0; i < 4; ++i)
#pragma unroll
        for (int h = 0; h < 2; ++h) {
            float4 xv = *(const float4*)(x + ((size_t)(wb + i) * NN + n) * DD
                                           + 4 * d8 + 32 * h);
            xlo[i][h] = (v2f){xv.x, xv.y};
            xhi[i][h] = (v2f){xv.z, xv.w};
        }

    const float* tb = tmpl + (size_t)k8 * NN * DD + (size_t)n * DD + 4 * d8;

    float bestd  = 3.4e38f;
    int   bestcb = 0;

    const bool u0 = (lane & 1) != 0;
    const bool u1 = (lane & 2) != 0;

#pragma unroll
    for (int cb = 0; cb < KK; cb += 8) {
        // Two dense loads: 8 k-rows x 128B halves.
        float4 t0 = *(const float4*)(tb + (size_t)cb * NN * DD);
        float4 t1 = *(const float4*)(tb + (size_t)cb * NN * DD + 32);
        v2f tl0 = (v2f){t0.x, t0.y}, th0 = (v2f){t0.z, t0.w};
        v2f tl1 = (v2f){t1.x, t1.y}, th1 = (v2f){t1.z, t1.w};

        float p[4];
#pragma unroll
        for (int i = 0; i < 4; ++i) {
            v2f dl0 = xlo[i][0] - tl0, dh0 = xhi[i][0] - th0;
            v2f dl1 = xlo[i][1] - tl1, dh1 = xhi[i][1] - th1;
            v2f s0v = dl0 * dl0 + dh0 * dh0;   // pk_mul + pk_fma
            v2f s1v = dl1 * dl1 + dh1 * dh1;
            v2f sv  = s0v + s1v;
            p[i] = sv.x + sv.y;
        }

        // R6-verified butterfly over lane bits 0,1 (b-fold + d-pair reduce).
        float a0 = u0 ? p[2] : p[0];
        float s0 = u0 ? p[0] : p[2];
        float a1 = u0 ? p[3] : p[1];
        float s1 = u0 ? p[1] : p[3];
        float q0 = a0 + swz<0x041F>(s0);       // xor lane^1
        float q1 = a1 + swz<0x041F>(s1);
        float a  = u1 ? q1 : q0;
        float s  = u1 ? q0 : q1;
        float r  = a + swz<0x081F>(s);         // xor lane^2
        r += swz<0x101F>(r);                   // xor lane^4 completes 64-d sum

        // r = dist(b = wb + 2*bit0 + bit1, k = cb + k8). Strict < keeps the
        // earliest cb (first-index per lane); cb is an inline const (<=56).
        if (r < bestd) { bestd = r; bestcb = cb; }
    }

    int bestk = bestcb + k8;

    // Lex-min across the 8 k8 groups (lane bits 3,4,5); first-index ties.
#pragma unroll
    for (int m = 8; m < 64; m <<= 1) {
        float od = __shfl_xor(bestd, m);
        int   ok = __shfl_xor(bestk, m);
        if (od < bestd || (od == bestd && ok < bestk)) { bestd = od; bestk = ok; }
    }

    // Lanes 0..3 hold final (bestd,bestk) for b = wb + 2*bit0 + bit1.
    if (lane < 4) {
        const int b = wb + 2 * (lane & 1) + ((lane >> 1) & 1);
        const size_t BN = (size_t)BB * NN;
        const size_t o  = (size_t)b * NN + n;
        out[o]          = (bestd <= 0.5f) ? 1.0f : 0.0f;  // masks[0] @0.5
        out[BN + o]     = (bestd <= 1.0f) ? 1.0f : 0.0f;  // masks[1] @1.0
        out[2 * BN + o] = bestd;                          // min_dists
        out[3 * BN + o] = (float)tcls[bestk];             // pred_classes
    }
}

extern "C" void kernel_launch(void* const* d_in, const int* in_sizes, int n_in,
                              void* d_out, int out_size, void* d_ws, size_t ws_size,
                              hipStream_t stream) {
    const float* x    = (const float*)d_in[0];   // frame_embeddings [16,16384,64]
    const float* tmpl = (const float*)d_in[1];   // templates       [64,16384,64]
    const int*   tcls = (const int*)d_in[2];     // template_classes [64]
    float* out = (float*)d_out;

    dim3 grid(NN);        // 16384 blocks: block = pixel, 4 waves = 16 b
    dim3 block(256);
    openset_kernel<<<grid, block, 0, stream>>>(x, tmpl, tcls, out);
}